// Round 1
// 532.124 us; speedup vs baseline: 1.1795x; 1.1795x over previous
//
#include <hip/hip_runtime.h>
#include <math.h>

#define Bq 64
#define Hq 256
#define Lq 1024
#define HLq (Hq*Lq)        // 262144
#define BHLq (Bq*Hq*Lq)    // 16777216
#define HNq (Hq*64)        // 16384

typedef __attribute__((ext_vector_type(8))) short bf16x8;
typedef __attribute__((ext_vector_type(4))) float f32x4;

__device__ __forceinline__ float sigmoidf_(float x){ return 1.f/(1.f+expf(-x)); }
__device__ __forceinline__ unsigned short f2bf(float f){
  unsigned u = __float_as_uint(f);
  u += 0x7FFF + ((u>>16)&1);
  return (unsigned short)(u>>16);
}
__device__ __forceinline__ float bf2f(unsigned short h){ return __uint_as_float(((unsigned)h)<<16); }

// ---------------- K1a: ada linear partials. Grid (32 o-tiles, 16 k-chunks), 512 blocks.
// Each block: 64b x 64o x 64k fp32 partial GEMM. emb+silu recomputed straight into LDS.
__global__ __launch_bounds__(256) void k_ada2(const int* __restrict__ tptr,
        const float* __restrict__ ada_w, float* __restrict__ Part){
  __shared__ float Es[64][68];   // stride 68 fl: bank = (4*row + k) % 32
  __shared__ float Ws[64][68];
  const int tid = threadIdx.x;
  const int o0 = blockIdx.x * 64;
  const int kc = blockIdx.y;
  const int k0 = kc * 64;
  const float ci = -logf(10000.f) / 511.f;
  // Es[b][kk] = silu(sin/cos(t[b] * f_k)), k = k0+kk  (k<512 uniform per block)
  #pragma unroll
  for (int it = 0; it < 4; ++it){
    int fidx = it*256 + tid;
    int row = fidx >> 4;        // b
    int c4  = fidx & 15;
    float tb = (float)tptr[row];
    float4 v;
    float* vp = &v.x;
    #pragma unroll
    for (int q = 0; q < 4; ++q){
      int k = k0 + c4*4 + q;
      float f = expf(ci * (float)(k & 511));
      float arg = tb * f;
      float s = (k < 512) ? sinf(arg) : cosf(arg);
      vp[q] = s * sigmoidf_(s);
    }
    *(float4*)&Es[row][c4*4] = v;
  }
  #pragma unroll
  for (int it = 0; it < 4; ++it){
    int fidx = it*256 + tid;
    int row = fidx >> 4;        // o
    int c4  = fidx & 15;
    *(float4*)&Ws[row][c4*4] = *(const float4*)(ada_w + (size_t)(o0+row)*1024 + k0 + c4*4);
  }
  __syncthreads();
  // thread tile: b = (tid>>4)+16i, o = (tid&15)+16j  (4x4 register tile)
  float acc[4][4] = {};
  #pragma unroll
  for (int ks = 0; ks < 16; ++ks){
    int k = ks*4;
    float4 ev[4], wv[4];
    #pragma unroll
    for (int i=0;i<4;++i) ev[i] = *(const float4*)&Es[(tid>>4) + 16*i][k];
    #pragma unroll
    for (int j=0;j<4;++j) wv[j] = *(const float4*)&Ws[(tid&15) + 16*j][k];
    #pragma unroll
    for (int i=0;i<4;++i)
      #pragma unroll
      for (int j=0;j<4;++j)
        acc[i][j] += ev[i].x*wv[j].x + ev[i].y*wv[j].y + ev[i].z*wv[j].z + ev[i].w*wv[j].w;
  }
  float* pbase = Part + (size_t)kc*131072 + o0;   // Part[kc][b][o]
  #pragma unroll
  for (int i=0;i<4;++i){
    int b = (tid>>4) + 16*i;
    #pragma unroll
    for (int j=0;j<4;++j){
      int o = (tid&15) + 16*j;
      pbase[(size_t)b*2048 + o] = acc[i][j];
    }
  }
}

// ---------------- K1b: reduce 16 K-partials + bias -> scsh (B x 2048)
__global__ void k_red(const float* __restrict__ Part, const float* __restrict__ ada_b,
                      float* __restrict__ scsh){
  int idx = blockIdx.x*256 + threadIdx.x;   // float4 index, 32768 total
  float4 s = ((const float4*)ada_b)[idx & 511];
  #pragma unroll
  for (int p = 0; p < 16; ++p){
    float4 u = ((const float4*)Part)[p*32768 + idx];
    s.x += u.x; s.y += u.y; s.z += u.z; s.w += u.w;
  }
  ((float4*)scsh)[idx] = s;
}

// ---------------- K2: AdaLayerNorm over L per (b,h) row -> Ax (fp32)
__global__ void k_adaln(const float* __restrict__ x, const float* __restrict__ scsh,
                        float* __restrict__ A){
  const int bid = blockIdx.x;        // b*H + h
  const int b = bid >> 8;
  const int tid = threadIdx.x;
  const float4* row = (const float4*)(x + (size_t)bid*1024);
  float4 v = row[tid];
  float s = v.x+v.y+v.z+v.w;
  float ss = v.x*v.x+v.y*v.y+v.z*v.z+v.w*v.w;
  #pragma unroll
  for (int off=32; off; off>>=1){ s += __shfl_xor(s,off); ss += __shfl_xor(ss,off); }
  __shared__ float rs_[4], rss_[4];
  int lane = tid & 63, w = tid >> 6;
  if (!lane){ rs_[w]=s; rss_[w]=ss; }
  __syncthreads();
  s  = rs_[0]+rs_[1]+rs_[2]+rs_[3];
  ss = rss_[0]+rss_[1]+rss_[2]+rss_[3];
  float mean = s * (1.f/1024.f);
  float var  = ss*(1.f/1024.f) - mean*mean;
  float rstd = rsqrtf(var + 1e-5f);
  float4 sc = ((const float4*)(scsh + b*2048))[tid];
  float4 sh = ((const float4*)(scsh + b*2048 + 1024))[tid];
  float4 o;
  o.x = (v.x-mean)*rstd*(1.f+sc.x) + sh.x;
  o.y = (v.y-mean)*rstd*(1.f+sc.y) + sh.y;
  o.z = (v.z-mean)*rstd*(1.f+sc.z) + sh.z;
  o.w = (v.w-mean)*rstd*(1.f+sc.w) + sh.w;
  ((float4*)(A + (size_t)bid*1024))[tid] = o;
}

// ---------------- K3: channel LayerNorm over H per (b,l) -> z in bf16
__global__ void k_chln(const float* __restrict__ A, const float* __restrict__ nw,
                       const float* __restrict__ nb, unsigned short* __restrict__ Zb){
  const int b = blockIdx.y;
  const int l = blockIdx.x*256 + threadIdx.x;
  const float* base = A + (size_t)b*HLq + l;
  float s=0.f, ss=0.f;
  for (int h=0; h<256; ++h){ float v = base[h*1024]; s+=v; ss+=v*v; }
  float mean = s*(1.f/256.f);
  float var  = ss*(1.f/256.f) - mean*mean;
  float rstd = rsqrtf(var+1e-5f);
  unsigned short* zb = Zb + (size_t)b*HLq + l;
  for (int h=0; h<256; ++h){
    float v = base[h*1024];
    zb[h*1024] = f2bf((v-mean)*rstd*nw[h] + nb[h]);
  }
}

// ---------------- K4: SSM kernels K0/K1 (2,H,L) via direct Vandermonde sum (fp32)
__global__ void k_ssmk(const float* __restrict__ log_dt, const float* __restrict__ A_re,
                       const float* __restrict__ A_im, const float* __restrict__ C_re,
                       const float* __restrict__ C_im, float* __restrict__ Kbuf){
  const int h = blockIdx.y;
  const int tid = threadIdx.x;
  __shared__ float dre[64], dim_[64], c0r[64], c0i[64], c1r[64], c1i[64];
  if (tid < 64){
    int n = tid;
    float dt = expf(log_dt[h]);
    float Ar = -expf(A_re[h*64+n]);
    float Ai = A_im[h*64+n];
    float dr = dt*Ar, di = dt*Ai;
    float er = expf(dr);
    float dAr = er*cosf(di), dAi = er*sinf(di);
    float den = Ar*Ar + Ai*Ai;
    float nr = dAr - 1.f, ni = dAi;
    float qr = (nr*Ar + ni*Ai)/den;
    float qi = (ni*Ar - nr*Ai)/den;
    float C0r = C_re[h*64+n],       C0i = C_im[h*64+n];
    float C1r = C_re[HNq + h*64+n], C1i = C_im[HNq + h*64+n];
    c0r[n] = C0r*qr - C0i*qi; c0i[n] = C0r*qi + C0i*qr;
    c1r[n] = C1r*qr - C1i*qi; c1i[n] = C1r*qi + C1i*qr;
    dre[n] = dr; dim_[n] = di;
  }
  __syncthreads();
  int l = blockIdx.x*256 + tid;
  float lf = (float)l;
  float a0=0.f, a1=0.f;
  for (int n=0;n<64;++n){
    float e  = expf(lf*dre[n]);
    float ph = lf*dim_[n];
    float wr = e*cosf(ph), wi = e*sinf(ph);
    a0 += c0r[n]*wr - c0i[n]*wi;
    a1 += c1r[n]*wr - c1i[n]*wi;
  }
  Kbuf[h*1024 + l]       = 2.f*a0;
  Kbuf[HLq + h*1024 + l] = 2.f*a1;
}

// ---------------- K5: bidirectional Toeplitz conv via bf16 MFMA + D*z + GELU -> Cb bf16
// Per block: h fixed, M=64 batches, N=512 outputs, K=1024.
// B operand read straight from 8 shifted copies of the reversed kernel vector.
__global__ __launch_bounds__(256,2) void k_conv(const unsigned short* __restrict__ Zb,
        const float* __restrict__ Kbuf, const float* __restrict__ Dp,
        unsigned short* __restrict__ Cb){
  __shared__ unsigned short kcopy[8][2056];   // stride 2056 el = 1028 dw = 4 mod 32 (bank spread)
  __shared__ unsigned short As[64][136];      // z tile, Kc=128, +8 pad
  const int tid = threadIdx.x;
  const int h  = blockIdx.y;
  const int l0 = blockIdx.x * 512;
  const float* K0 = Kbuf + h*1024;
  const float* K1 = Kbuf + HLq + h*1024;
  // krev[p] = kf[2046-p]; kf[1023+d] = d>=0 ? K0[d] : K1[-d-1]; copy[s][i] = krev[i+s]
  for (int idx = tid; idx < 8*2056; idx += 256){
    int s = idx / 2056;
    int i = idx - s*2056;
    int q = 2046 - i - s;
    float v = 0.f;
    if (q >= 0) v = (q >= 1023) ? K0[q-1023] : K1[1022-q];
    kcopy[s][i] = f2bf(v);
  }
  const int lane = tid & 63;
  const int w    = tid >> 6;
  const int ln   = lane & 15;
  const int quad = lane >> 4;
  int kofs[8];
  #pragma unroll
  for (int nt=0; nt<8; ++nt){
    int l = l0 + w*128 + nt*16 + ln;
    int d = 1023 - l;              // krev base = d + j
    int s = d & 7;
    kofs[nt] = s*2056 + (d - s) + quad*8;   // 16B-aligned element offset
  }
  const unsigned short* kbase = &kcopy[0][0];
  f32x4 acc[4][8] = {};
  for (int c = 0; c < 8; ++c){
    __syncthreads();
    #pragma unroll
    for (int pass = 0; pass < 4; ++pass){
      int b = pass*16 + (tid>>4);
      int col = (tid & 15)*8;
      *(uint4*)&As[b][col] = *(const uint4*)(Zb + ((size_t)b*256 + h)*1024 + c*128 + col);
    }
    __syncthreads();
    #pragma unroll
    for (int ks = 0; ks < 4; ++ks){
      int kk = ks*32 + quad*8;
      bf16x8 af[4];
      #pragma unroll
      for (int mt=0; mt<4; ++mt) af[mt] = *(const bf16x8*)&As[mt*16+ln][kk];
      int jb = c*128 + ks*32;
      bf16x8 bv[8];
      #pragma unroll
      for (int nt=0; nt<8; ++nt) bv[nt] = *(const bf16x8*)(kbase + kofs[nt] + jb);
      #pragma unroll
      for (int mt=0; mt<4; ++mt)
        #pragma unroll
        for (int nt=0; nt<8; ++nt)
          acc[mt][nt] = __builtin_amdgcn_mfma_f32_16x16x32_bf16(af[mt], bv[nt], acc[mt][nt], 0,0,0);
    }
  }
  float Dh = Dp[h];
  #pragma unroll
  for (int mt=0; mt<4; ++mt){
    #pragma unroll
    for (int reg=0; reg<4; ++reg){
      int b = mt*16 + quad*4 + reg;
      const unsigned short* zrow = Zb + ((size_t)b*256+h)*1024;
      unsigned short* crow = Cb + ((size_t)b*256+h)*1024;
      #pragma unroll
      for (int nt=0; nt<8; ++nt){
        int l = l0 + w*128 + nt*16 + ln;
        float y = acc[mt][nt][reg] + Dh*bf2f(zrow[l]);
        float g = 0.5f*y*(1.f + erff(y*0.70710678118f));
        crow[l] = f2bf(g);
      }
    }
  }
}

// ---------------- K6: x2 = out_w @ u + out_b + x1 ; g = tanh(x2)*sigmoid(x2)  (bf16 MFMA)
__global__ __launch_bounds__(256,2) void k_gate(const unsigned short* __restrict__ U,
        const float* __restrict__ W, const float* __restrict__ bias,
        const float* __restrict__ Ax, unsigned short* __restrict__ G){
  __shared__ unsigned short Ws[64][72];
  __shared__ unsigned short Us[256][72];
  const int tid = threadIdx.x;
  const int l0 = blockIdx.x * 256;
  const int o0 = blockIdx.y * 64;
  const int b  = blockIdx.z;
  const int lane = tid & 63, w = tid>>6, ln = lane&15, quad = lane>>4;
  f32x4 acc[4][4] = {};
  for (int ch = 0; ch < 4; ++ch){
    int ic0 = ch*64;
    __syncthreads();
    { // Ws: 64 o x 64 i (fp32 -> bf16)
      int o = tid & 63;
      int i = (tid >> 6) * 16;
      const float* wsrc = W + (size_t)(o0+o)*256 + ic0 + i;
      unsigned pk[8];
      #pragma unroll
      for (int r=0;r<8;++r) pk[r] = (unsigned)f2bf(wsrc[2*r]) | ((unsigned)f2bf(wsrc[2*r+1])<<16);
      uint4* dst = (uint4*)&Ws[o][i];
      dst[0] = make_uint4(pk[0],pk[1],pk[2],pk[3]);
      dst[1] = make_uint4(pk[4],pk[5],pk[6],pk[7]);
    }
    // Us: [l][i] = U[b][ic0+i][l0+l]  (transpose staging, 4 i per 8B write)
    #pragma unroll
    for (int it = 0; it < 16; ++it){
      int i4 = (tid>>6) + 4*(it&3);
      int l  = (it>>2)*64 + (tid&63);
      const unsigned short* usrc = U + ((size_t)b*256 + ic0 + i4*4)*1024 + l0 + l;
      unsigned short e0 = usrc[0], e1 = usrc[1024], e2 = usrc[2048], e3 = usrc[3072];
      uint2 val; val.x = (unsigned)e0 | ((unsigned)e1<<16); val.y = (unsigned)e2 | ((unsigned)e3<<16);
      *(uint2*)&Us[l][i4*4] = val;
    }
    __syncthreads();
    #pragma unroll
    for (int ks = 0; ks < 2; ++ks){
      int kk = ks*32 + quad*8;
      bf16x8 af[4], bv[4];
      #pragma unroll
      for (int mt=0;mt<4;++mt) af[mt] = *(const bf16x8*)&Ws[mt*16+ln][kk];
      #pragma unroll
      for (int nt=0;nt<4;++nt) bv[nt] = *(const bf16x8*)&Us[w*64+nt*16+ln][kk];
      #pragma unroll
      for (int mt=0;mt<4;++mt)
        #pragma unroll
        for (int nt=0;nt<4;++nt)
          acc[mt][nt] = __builtin_amdgcn_mfma_f32_16x16x32_bf16(af[mt], bv[nt], acc[mt][nt],0,0,0);
    }
  }
  #pragma unroll
  for (int mt=0;mt<4;++mt){
    #pragma unroll
    for (int reg=0;reg<4;++reg){
      int o = o0 + mt*16 + quad*4 + reg;
      float bo = bias[o];
      const float* arow = Ax + ((size_t)b*256 + o)*1024;
      unsigned short* grow = G + ((size_t)b*256 + o)*1024;
      #pragma unroll
      for (int nt=0;nt<4;++nt){
        int l = l0 + w*64 + nt*16 + ln;
        float v = acc[mt][nt][reg] + bo + arow[l];
        float g = tanhf(v)*sigmoidf_(v);
        grow[l] = f2bf(g);
      }
    }
  }
}

// ---------------- K7: out1 = lin1@g + b1 + x1 ; out2 = lin2@g + b2  (bf16 MFMA, dual acc)
__global__ __launch_bounds__(256,2) void k_out(const unsigned short* __restrict__ G,
        const float* __restrict__ W1, const float* __restrict__ b1,
        const float* __restrict__ W2, const float* __restrict__ b2,
        const float* __restrict__ Ax, float* __restrict__ out){
  __shared__ unsigned short W1s[64][72];
  __shared__ unsigned short W2s[64][72];
  __shared__ unsigned short Us[256][72];
  const int tid = threadIdx.x;
  const int l0 = blockIdx.x * 256;
  const int o0 = blockIdx.y * 64;
  const int b  = blockIdx.z;
  const int lane = tid & 63, w = tid>>6, ln = lane&15, quad = lane>>4;
  f32x4 acc1[4][4] = {};
  f32x4 acc2[4][4] = {};
  for (int ch = 0; ch < 4; ++ch){
    int ic0 = ch*64;
    __syncthreads();
    {
      int o = tid & 63;
      int i = (tid >> 6) * 16;
      const float* w1src = W1 + (size_t)(o0+o)*256 + ic0 + i;
      const float* w2src = W2 + (size_t)(o0+o)*256 + ic0 + i;
      unsigned pk[8];
      #pragma unroll
      for (int r=0;r<8;++r) pk[r] = (unsigned)f2bf(w1src[2*r]) | ((unsigned)f2bf(w1src[2*r+1])<<16);
      uint4* dst1 = (uint4*)&W1s[o][i];
      dst1[0] = make_uint4(pk[0],pk[1],pk[2],pk[3]);
      dst1[1] = make_uint4(pk[4],pk[5],pk[6],pk[7]);
      #pragma unroll
      for (int r=0;r<8;++r) pk[r] = (unsigned)f2bf(w2src[2*r]) | ((unsigned)f2bf(w2src[2*r+1])<<16);
      uint4* dst2 = (uint4*)&W2s[o][i];
      dst2[0] = make_uint4(pk[0],pk[1],pk[2],pk[3]);
      dst2[1] = make_uint4(pk[4],pk[5],pk[6],pk[7]);
    }
    #pragma unroll
    for (int it = 0; it < 16; ++it){
      int i4 = (tid>>6) + 4*(it&3);
      int l  = (it>>2)*64 + (tid&63);
      const unsigned short* usrc = G + ((size_t)b*256 + ic0 + i4*4)*1024 + l0 + l;
      unsigned short e0 = usrc[0], e1 = usrc[1024], e2 = usrc[2048], e3 = usrc[3072];
      uint2 val; val.x = (unsigned)e0 | ((unsigned)e1<<16); val.y = (unsigned)e2 | ((unsigned)e3<<16);
      *(uint2*)&Us[l][i4*4] = val;
    }
    __syncthreads();
    #pragma unroll
    for (int ks = 0; ks < 2; ++ks){
      int kk = ks*32 + quad*8;
      bf16x8 bv[4];
      #pragma unroll
      for (int nt=0;nt<4;++nt) bv[nt] = *(const bf16x8*)&Us[w*64+nt*16+ln][kk];
      #pragma unroll
      for (int mt=0;mt<4;++mt){
        bf16x8 a1 = *(const bf16x8*)&W1s[mt*16+ln][kk];
        #pragma unroll
        for (int nt=0;nt<4;++nt)
          acc1[mt][nt] = __builtin_amdgcn_mfma_f32_16x16x32_bf16(a1, bv[nt], acc1[mt][nt],0,0,0);
      }
      #pragma unroll
      for (int mt=0;mt<4;++mt){
        bf16x8 a2 = *(const bf16x8*)&W2s[mt*16+ln][kk];
        #pragma unroll
        for (int nt=0;nt<4;++nt)
          acc2[mt][nt] = __builtin_amdgcn_mfma_f32_16x16x32_bf16(a2, bv[nt], acc2[mt][nt],0,0,0);
      }
    }
  }
  #pragma unroll
  for (int mt=0;mt<4;++mt){
    #pragma unroll
    for (int reg=0;reg<4;++reg){
      int o = o0 + mt*16 + quad*4 + reg;
      float bo1 = b1[o], bo2 = b2[o];
      const float* arow = Ax + ((size_t)b*256 + o)*1024;
      float* o1row = out + ((size_t)b*256 + o)*1024;
      float* o2row = o1row + BHLq;
      #pragma unroll
      for (int nt=0;nt<4;++nt){
        int l = l0 + w*64 + nt*16 + ln;
        o1row[l] = acc1[mt][nt][reg] + bo1 + arow[l];
        o2row[l] = acc2[mt][nt][reg] + bo2;
      }
    }
  }
}

extern "C" void kernel_launch(void* const* d_in, const int* in_sizes, int n_in,
                              void* d_out, int out_size, void* d_ws, size_t ws_size,
                              hipStream_t stream){
  const float* x      = (const float*)d_in[0];
  const int*   t      = (const int*)  d_in[1];
  const float* ada_w  = (const float*)d_in[2];
  const float* ada_b  = (const float*)d_in[3];
  const float* norm_w = (const float*)d_in[4];
  const float* norm_b = (const float*)d_in[5];
  const float* log_dt = (const float*)d_in[6];
  const float* A_re   = (const float*)d_in[7];
  const float* A_im   = (const float*)d_in[8];
  const float* C_re   = (const float*)d_in[9];
  const float* C_im   = (const float*)d_in[10];
  const float* Dp     = (const float*)d_in[11];
  const float* out_w  = (const float*)d_in[12];
  const float* out_b  = (const float*)d_in[13];
  const float* lin1_w = (const float*)d_in[14];
  const float* lin1_b = (const float*)d_in[15];
  const float* lin2_w = (const float*)d_in[16];
  const float* lin2_b = (const float*)d_in[17];

  float* Ax            = (float*)d_ws;                     // x1 fp32, BHL
  unsigned short* Zb   = (unsigned short*)(Ax + BHLq);     // z bf16, BHL
  unsigned short* Cb   = Zb + BHLq;                        // gelu(y) bf16, BHL
  float* Kbuf          = (float*)(Cb + BHLq);              // 2*H*L fp32
  float* Part          = Kbuf + 2*HLq;                     // 16 x B x 2048 fp32 partials
  float* scsh          = Part + 16*64*2048;                // B*2048 fp32
  unsigned short* Gb   = Zb;                               // gate g bf16 aliases dead z
  float* out           = (float*)d_out;

  k_ada2  <<<dim3(32, 16), 256, 0, stream>>>(t, ada_w, Part);
  k_red   <<<128, 256, 0, stream>>>(Part, ada_b, scsh);
  k_adaln <<<Bq*Hq, 256, 0, stream>>>(x, scsh, Ax);
  k_chln  <<<dim3(4, Bq), 256, 0, stream>>>(Ax, norm_w, norm_b, Zb);
  k_ssmk  <<<dim3(4, Hq), 256, 0, stream>>>(log_dt, A_re, A_im, C_re, C_im, Kbuf);
  k_conv  <<<dim3(2, Hq), 256, 0, stream>>>(Zb, Kbuf, Dp, Cb);
  k_gate  <<<dim3(4, 4, Bq), 256, 0, stream>>>(Cb, out_w, out_b, Ax, Gb);
  k_out   <<<dim3(4, 4, Bq), 256, 0, stream>>>(Gb, lin1_w, lin1_b, lin2_w, lin2_b, Ax, out);
}

// Round 2
// 491.918 us; speedup vs baseline: 1.2759x; 1.0817x over previous
//
#include <hip/hip_runtime.h>
#include <math.h>

#define Bq 64
#define Hq 256
#define Lq 1024
#define HLq (Hq*Lq)        // 262144
#define BHLq (Bq*Hq*Lq)    // 16777216
#define HNq (Hq*64)        // 16384

typedef __attribute__((ext_vector_type(8))) short bf16x8;
typedef __attribute__((ext_vector_type(4))) float f32x4;

__device__ __forceinline__ float sigmoidf_(float x){ return 1.f/(1.f+expf(-x)); }
__device__ __forceinline__ unsigned short f2bf(float f){
  unsigned u = __float_as_uint(f);
  u += 0x7FFF + ((u>>16)&1);
  return (unsigned short)(u>>16);
}
__device__ __forceinline__ float bf2f(unsigned short h){ return __uint_as_float(((unsigned)h)<<16); }

// ---------------- K1a: ada linear partials. Grid (32 o-tiles, 16 k-chunks), 512 blocks.
__global__ __launch_bounds__(256) void k_ada2(const int* __restrict__ tptr,
        const float* __restrict__ ada_w, float* __restrict__ Part){
  __shared__ float Es[64][68];
  __shared__ float Ws[64][68];
  const int tid = threadIdx.x;
  const int o0 = blockIdx.x * 64;
  const int kc = blockIdx.y;
  const int k0 = kc * 64;
  const float ci = -logf(10000.f) / 511.f;
  #pragma unroll
  for (int it = 0; it < 4; ++it){
    int fidx = it*256 + tid;
    int row = fidx >> 4;        // b
    int c4  = fidx & 15;
    float tb = (float)tptr[row];
    float4 v;
    float* vp = &v.x;
    #pragma unroll
    for (int q = 0; q < 4; ++q){
      int k = k0 + c4*4 + q;
      float f = expf(ci * (float)(k & 511));
      float arg = tb * f;
      float s = (k < 512) ? sinf(arg) : cosf(arg);
      vp[q] = s * sigmoidf_(s);
    }
    *(float4*)&Es[row][c4*4] = v;
  }
  #pragma unroll
  for (int it = 0; it < 4; ++it){
    int fidx = it*256 + tid;
    int row = fidx >> 4;        // o
    int c4  = fidx & 15;
    *(float4*)&Ws[row][c4*4] = *(const float4*)(ada_w + (size_t)(o0+row)*1024 + k0 + c4*4);
  }
  __syncthreads();
  float acc[4][4] = {};
  #pragma unroll
  for (int ks = 0; ks < 16; ++ks){
    int k = ks*4;
    float4 ev[4], wv[4];
    #pragma unroll
    for (int i=0;i<4;++i) ev[i] = *(const float4*)&Es[(tid>>4) + 16*i][k];
    #pragma unroll
    for (int j=0;j<4;++j) wv[j] = *(const float4*)&Ws[(tid&15) + 16*j][k];
    #pragma unroll
    for (int i=0;i<4;++i)
      #pragma unroll
      for (int j=0;j<4;++j)
        acc[i][j] += ev[i].x*wv[j].x + ev[i].y*wv[j].y + ev[i].z*wv[j].z + ev[i].w*wv[j].w;
  }
  float* pbase = Part + (size_t)kc*131072 + o0;   // Part[kc][b][o]
  #pragma unroll
  for (int i=0;i<4;++i){
    int b = (tid>>4) + 16*i;
    #pragma unroll
    for (int j=0;j<4;++j){
      int o = (tid&15) + 16*j;
      pbase[(size_t)b*2048 + o] = acc[i][j];
    }
  }
}

// ---------------- K1b: reduce 16 K-partials + bias -> scsh (B x 2048)
__global__ void k_red(const float* __restrict__ Part, const float* __restrict__ ada_b,
                      float* __restrict__ scsh){
  int idx = blockIdx.x*256 + threadIdx.x;   // float4 index, 32768 total
  float4 s = ((const float4*)ada_b)[idx & 511];
  #pragma unroll
  for (int p = 0; p < 16; ++p){
    float4 u = ((const float4*)Part)[p*32768 + idx];
    s.x += u.x; s.y += u.y; s.z += u.z; s.w += u.w;
  }
  ((float4*)scsh)[idx] = s;
}

// ---------------- K1c: convert out_w / lin1_w / lin2_w (256x256 fp32) -> bf16, L2-resident
__global__ void k_wcvt(const float* __restrict__ w0, const float* __restrict__ w1,
                       const float* __restrict__ w2, unsigned short* __restrict__ wb){
  int idx = blockIdx.x*256 + threadIdx.x;   // float4 units, 49152 total
  const float* src = (idx < 16384) ? w0 : ((idx < 32768) ? w1 : w2);
  int loc = idx & 16383;
  float4 v = ((const float4*)src)[loc];
  uint2 pk;
  pk.x = (unsigned)f2bf(v.x) | ((unsigned)f2bf(v.y)<<16);
  pk.y = (unsigned)f2bf(v.z) | ((unsigned)f2bf(v.w)<<16);
  ((uint2*)wb)[idx] = pk;
}

// ---------------- K2: AdaLayerNorm over L per (b,h) row -> Ax (fp32)
__global__ void k_adaln(const float* __restrict__ x, const float* __restrict__ scsh,
                        float* __restrict__ A){
  const int bid = blockIdx.x;        // b*H + h
  const int b = bid >> 8;
  const int tid = threadIdx.x;
  const float4* row = (const float4*)(x + (size_t)bid*1024);
  float4 v = row[tid];
  float s = v.x+v.y+v.z+v.w;
  float ss = v.x*v.x+v.y*v.y+v.z*v.z+v.w*v.w;
  #pragma unroll
  for (int off=32; off; off>>=1){ s += __shfl_xor(s,off); ss += __shfl_xor(ss,off); }
  __shared__ float rs_[4], rss_[4];
  int lane = tid & 63, w = tid >> 6;
  if (!lane){ rs_[w]=s; rss_[w]=ss; }
  __syncthreads();
  s  = rs_[0]+rs_[1]+rs_[2]+rs_[3];
  ss = rss_[0]+rss_[1]+rss_[2]+rss_[3];
  float mean = s * (1.f/1024.f);
  float var  = ss*(1.f/1024.f) - mean*mean;
  float rstd = rsqrtf(var + 1e-5f);
  float4 sc = ((const float4*)(scsh + b*2048))[tid];
  float4 sh = ((const float4*)(scsh + b*2048 + 1024))[tid];
  float4 o;
  o.x = (v.x-mean)*rstd*(1.f+sc.x) + sh.x;
  o.y = (v.y-mean)*rstd*(1.f+sc.y) + sh.y;
  o.z = (v.z-mean)*rstd*(1.f+sc.z) + sh.z;
  o.w = (v.w-mean)*rstd*(1.f+sc.w) + sh.w;
  ((float4*)(A + (size_t)bid*1024))[tid] = o;
}

// ---------------- K3: channel LayerNorm over H per (b,l) -> z in bf16
__global__ void k_chln(const float* __restrict__ A, const float* __restrict__ nw,
                       const float* __restrict__ nb, unsigned short* __restrict__ Zb){
  const int b = blockIdx.y;
  const int l = blockIdx.x*256 + threadIdx.x;
  const float* base = A + (size_t)b*HLq + l;
  float s=0.f, ss=0.f;
  for (int h=0; h<256; ++h){ float v = base[h*1024]; s+=v; ss+=v*v; }
  float mean = s*(1.f/256.f);
  float var  = ss*(1.f/256.f) - mean*mean;
  float rstd = rsqrtf(var+1e-5f);
  unsigned short* zb = Zb + (size_t)b*HLq + l;
  for (int h=0; h<256; ++h){
    float v = base[h*1024];
    zb[h*1024] = f2bf((v-mean)*rstd*nw[h] + nb[h]);
  }
}

// ---------------- K4: SSM kernels K0/K1 (2,H,L) via direct Vandermonde sum (fp32)
__global__ void k_ssmk(const float* __restrict__ log_dt, const float* __restrict__ A_re,
                       const float* __restrict__ A_im, const float* __restrict__ C_re,
                       const float* __restrict__ C_im, float* __restrict__ Kbuf){
  const int h = blockIdx.y;
  const int tid = threadIdx.x;
  __shared__ float dre[64], dim_[64], c0r[64], c0i[64], c1r[64], c1i[64];
  if (tid < 64){
    int n = tid;
    float dt = expf(log_dt[h]);
    float Ar = -expf(A_re[h*64+n]);
    float Ai = A_im[h*64+n];
    float dr = dt*Ar, di = dt*Ai;
    float er = expf(dr);
    float dAr = er*cosf(di), dAi = er*sinf(di);
    float den = Ar*Ar + Ai*Ai;
    float nr = dAr - 1.f, ni = dAi;
    float qr = (nr*Ar + ni*Ai)/den;
    float qi = (ni*Ar - nr*Ai)/den;
    float C0r = C_re[h*64+n],       C0i = C_im[h*64+n];
    float C1r = C_re[HNq + h*64+n], C1i = C_im[HNq + h*64+n];
    c0r[n] = C0r*qr - C0i*qi; c0i[n] = C0r*qi + C0i*qr;
    c1r[n] = C1r*qr - C1i*qi; c1i[n] = C1r*qi + C1i*qr;
    dre[n] = dr; dim_[n] = di;
  }
  __syncthreads();
  int l = blockIdx.x*256 + tid;
  float lf = (float)l;
  float a0=0.f, a1=0.f;
  for (int n=0;n<64;++n){
    float e  = expf(lf*dre[n]);
    float ph = lf*dim_[n];
    float wr = e*cosf(ph), wi = e*sinf(ph);
    a0 += c0r[n]*wr - c0i[n]*wi;
    a1 += c1r[n]*wr - c1i[n]*wi;
  }
  Kbuf[h*1024 + l]       = 2.f*a0;
  Kbuf[HLq + h*1024 + l] = 2.f*a1;
}

// ---------------- K5: bidirectional Toeplitz conv via bf16 MFMA + D*z + GELU -> Cb bf16
__global__ __launch_bounds__(256,2) void k_conv(const unsigned short* __restrict__ Zb,
        const float* __restrict__ Kbuf, const float* __restrict__ Dp,
        unsigned short* __restrict__ Cb){
  __shared__ unsigned short kcopy[8][2056];   // stride 2056 el = 1028 dw = 4 mod 32 (bank spread)
  __shared__ unsigned short As[64][136];      // z tile, Kc=128, +8 pad
  const int tid = threadIdx.x;
  const int h  = blockIdx.y;
  const int l0 = blockIdx.x * 512;
  const float* K0 = Kbuf + h*1024;
  const float* K1 = Kbuf + HLq + h*1024;
  for (int idx = tid; idx < 8*2056; idx += 256){
    int s = idx / 2056;
    int i = idx - s*2056;
    int q = 2046 - i - s;
    float v = 0.f;
    if (q >= 0) v = (q >= 1023) ? K0[q-1023] : K1[1022-q];
    kcopy[s][i] = f2bf(v);
  }
  const int lane = tid & 63;
  const int w    = tid >> 6;
  const int ln   = lane & 15;
  const int quad = lane >> 4;
  int kofs[8];
  #pragma unroll
  for (int nt=0; nt<8; ++nt){
    int l = l0 + w*128 + nt*16 + ln;
    int d = 1023 - l;              // krev base = d + j
    int s = d & 7;
    kofs[nt] = s*2056 + (d - s) + quad*8;   // 16B-aligned element offset
  }
  const unsigned short* kbase = &kcopy[0][0];
  f32x4 acc[4][8] = {};
  for (int c = 0; c < 8; ++c){
    __syncthreads();
    #pragma unroll
    for (int pass = 0; pass < 4; ++pass){
      int b = pass*16 + (tid>>4);
      int col = (tid & 15)*8;
      *(uint4*)&As[b][col] = *(const uint4*)(Zb + ((size_t)b*256 + h)*1024 + c*128 + col);
    }
    __syncthreads();
    #pragma unroll
    for (int ks = 0; ks < 4; ++ks){
      int kk = ks*32 + quad*8;
      bf16x8 af[4];
      #pragma unroll
      for (int mt=0; mt<4; ++mt) af[mt] = *(const bf16x8*)&As[mt*16+ln][kk];
      int jb = c*128 + ks*32;
      bf16x8 bv[8];
      #pragma unroll
      for (int nt=0; nt<8; ++nt) bv[nt] = *(const bf16x8*)(kbase + kofs[nt] + jb);
      #pragma unroll
      for (int mt=0; mt<4; ++mt)
        #pragma unroll
        for (int nt=0; nt<8; ++nt)
          acc[mt][nt] = __builtin_amdgcn_mfma_f32_16x16x32_bf16(af[mt], bv[nt], acc[mt][nt], 0,0,0);
    }
  }
  float Dh = Dp[h];
  #pragma unroll
  for (int mt=0; mt<4; ++mt){
    #pragma unroll
    for (int reg=0; reg<4; ++reg){
      int b = mt*16 + quad*4 + reg;
      const unsigned short* zrow = Zb + ((size_t)b*256+h)*1024;
      unsigned short* crow = Cb + ((size_t)b*256+h)*1024;
      #pragma unroll
      for (int nt=0; nt<8; ++nt){
        int l = l0 + w*128 + nt*16 + ln;
        float y = acc[mt][nt][reg] + Dh*bf2f(zrow[l]);
        float g = 0.5f*y*(1.f + erff(y*0.70710678118f));
        crow[l] = f2bf(g);
      }
    }
  }
}

// ---------------- K6: FUSED gate + dual output GEMM.
// Per block: b fixed, 64-wide l-tile, 512 threads = 8 waves, wave owns 32 o-rows.
// x2 = out_w@u + out_b + Ax ; g = tanh(x2)*sigmoid(x2) (LDS round-trip only)
// out1 = lin1@g + b1 + Ax ; out2 = lin2@g + b2. Ax kept in registers between uses.
// Weights read direct from global as pre-converted bf16 (L2-resident, 384KB total).
__global__ __launch_bounds__(512,2) void k_fuse(const unsigned short* __restrict__ U,
        const unsigned short* __restrict__ Wob, const float* __restrict__ out_b,
        const unsigned short* __restrict__ W1b, const float* __restrict__ b1,
        const unsigned short* __restrict__ W2b, const float* __restrict__ b2,
        const float* __restrict__ Ax, float* __restrict__ out){
  __shared__ unsigned short Us[64][280];   // u[l][i], stride 280 el: 16B rows, 2-way max on b128 reads
  __shared__ unsigned short Gs[64][280];   // g[l][i]
  const int tid = threadIdx.x;
  const int l0 = blockIdx.x * 64;
  const int b  = blockIdx.y;
  const int lane = tid & 63, w = tid >> 6, ln = lane & 15, quad = lane >> 4;
  // ---- stage Us[l][i] = U[b][i][l0+l] (transpose, 4 i per uint2)
  {
    int l   = tid & 63;
    int grp = tid >> 6;            // 0..7
    #pragma unroll
    for (int it = 0; it < 8; ++it){
      int i4 = it*8 + grp;         // 0..63
      const unsigned short* usrc = U + ((size_t)b*256 + i4*4)*1024 + l0 + l;
      unsigned short e0 = usrc[0], e1 = usrc[1024], e2 = usrc[2048], e3 = usrc[3072];
      uint2 val; val.x = (unsigned)e0 | ((unsigned)e1<<16); val.y = (unsigned)e2 | ((unsigned)e3<<16);
      *(uint2*)&Us[l][i4*4] = val;
    }
  }
  __syncthreads();
  // ---- GEMM1: x2 tile for o in [w*32, w*32+32)
  f32x4 acc[2][4] = {};
  #pragma unroll
  for (int ks = 0; ks < 8; ++ks){
    int kk = ks*32 + quad*8;
    bf16x8 af[2], bv[4];
    #pragma unroll
    for (int mt=0;mt<2;++mt) af[mt] = *(const bf16x8*)(Wob + (size_t)(w*32+mt*16+ln)*256 + kk);
    #pragma unroll
    for (int nt=0;nt<4;++nt) bv[nt] = *(const bf16x8*)&Us[nt*16+ln][kk];
    #pragma unroll
    for (int mt=0;mt<2;++mt)
      #pragma unroll
      for (int nt=0;nt<4;++nt)
        acc[mt][nt] = __builtin_amdgcn_mfma_f32_16x16x32_bf16(af[mt], bv[nt], acc[mt][nt],0,0,0);
  }
  // ---- gate; cache Ax in regs for the out1 residual
  float axv[2][4][4];
  #pragma unroll
  for (int mt=0;mt<2;++mt){
    #pragma unroll
    for (int reg=0;reg<4;++reg){
      int o = w*32 + mt*16 + quad*4 + reg;
      float bo = out_b[o];
      const float* arow = Ax + ((size_t)b*256 + o)*1024 + l0;
      #pragma unroll
      for (int nt=0;nt<4;++nt){
        int l = nt*16 + ln;
        float a = arow[l];
        axv[mt][nt][reg] = a;
        float v = acc[mt][nt][reg] + bo + a;
        acc[mt][nt][reg] = tanhf(v)*sigmoidf_(v);
      }
    }
  }
  #pragma unroll
  for (int mt=0;mt<2;++mt){
    int ob = w*32 + mt*16 + quad*4;
    #pragma unroll
    for (int nt=0;nt<4;++nt){
      uint2 pk;
      pk.x = (unsigned)f2bf(acc[mt][nt][0]) | ((unsigned)f2bf(acc[mt][nt][1])<<16);
      pk.y = (unsigned)f2bf(acc[mt][nt][2]) | ((unsigned)f2bf(acc[mt][nt][3])<<16);
      *(uint2*)&Gs[nt*16+ln][ob] = pk;
    }
  }
  __syncthreads();
  // ---- GEMM2 (dual): out1/out2 over K=256 of g
  f32x4 acc1[2][4] = {}, acc2[2][4] = {};
  #pragma unroll
  for (int ks = 0; ks < 8; ++ks){
    int kk = ks*32 + quad*8;
    bf16x8 bv[4];
    #pragma unroll
    for (int nt=0;nt<4;++nt) bv[nt] = *(const bf16x8*)&Gs[nt*16+ln][kk];
    #pragma unroll
    for (int mt=0;mt<2;++mt){
      bf16x8 a1 = *(const bf16x8*)(W1b + (size_t)(w*32+mt*16+ln)*256 + kk);
      #pragma unroll
      for (int nt=0;nt<4;++nt)
        acc1[mt][nt] = __builtin_amdgcn_mfma_f32_16x16x32_bf16(a1, bv[nt], acc1[mt][nt],0,0,0);
      bf16x8 a2 = *(const bf16x8*)(W2b + (size_t)(w*32+mt*16+ln)*256 + kk);
      #pragma unroll
      for (int nt=0;nt<4;++nt)
        acc2[mt][nt] = __builtin_amdgcn_mfma_f32_16x16x32_bf16(a2, bv[nt], acc2[mt][nt],0,0,0);
    }
  }
  // ---- epilogue
  #pragma unroll
  for (int mt=0;mt<2;++mt){
    #pragma unroll
    for (int reg=0;reg<4;++reg){
      int o = w*32 + mt*16 + quad*4 + reg;
      float bo1 = b1[o], bo2 = b2[o];
      float* o1row = out + ((size_t)b*256 + o)*1024 + l0;
      float* o2row = o1row + BHLq;
      #pragma unroll
      for (int nt=0;nt<4;++nt){
        int l = nt*16 + ln;
        o1row[l] = acc1[mt][nt][reg] + bo1 + axv[mt][nt][reg];
        o2row[l] = acc2[mt][nt][reg] + bo2;
      }
    }
  }
}

extern "C" void kernel_launch(void* const* d_in, const int* in_sizes, int n_in,
                              void* d_out, int out_size, void* d_ws, size_t ws_size,
                              hipStream_t stream){
  const float* x      = (const float*)d_in[0];
  const int*   t      = (const int*)  d_in[1];
  const float* ada_w  = (const float*)d_in[2];
  const float* ada_b  = (const float*)d_in[3];
  const float* norm_w = (const float*)d_in[4];
  const float* norm_b = (const float*)d_in[5];
  const float* log_dt = (const float*)d_in[6];
  const float* A_re   = (const float*)d_in[7];
  const float* A_im   = (const float*)d_in[8];
  const float* C_re   = (const float*)d_in[9];
  const float* C_im   = (const float*)d_in[10];
  const float* Dp     = (const float*)d_in[11];
  const float* out_w  = (const float*)d_in[12];
  const float* out_b  = (const float*)d_in[13];
  const float* lin1_w = (const float*)d_in[14];
  const float* lin1_b = (const float*)d_in[15];
  const float* lin2_w = (const float*)d_in[16];
  const float* lin2_b = (const float*)d_in[17];

  float* Ax            = (float*)d_ws;                     // x1 fp32, BHL
  unsigned short* Zb   = (unsigned short*)(Ax + BHLq);     // z bf16, BHL
  unsigned short* Cb   = Zb + BHLq;                        // gelu(y) bf16, BHL
  float* Kbuf          = (float*)(Cb + BHLq);              // 2*H*L fp32
  float* Part          = Kbuf + 2*HLq;                     // 16 x B x 2048 fp32 partials
  float* scsh          = Part + 16*64*2048;                // B*2048 fp32
  unsigned short* wb   = (unsigned short*)(scsh + 64*2048);// 3 x 256*256 bf16 weights
  float* out           = (float*)d_out;

  k_wcvt  <<<192, 256, 0, stream>>>(out_w, lin1_w, lin2_w, wb);
  k_ada2  <<<dim3(32, 16), 256, 0, stream>>>(t, ada_w, Part);
  k_red   <<<128, 256, 0, stream>>>(Part, ada_b, scsh);
  k_adaln <<<Bq*Hq, 256, 0, stream>>>(x, scsh, Ax);
  k_chln  <<<dim3(4, Bq), 256, 0, stream>>>(Ax, norm_w, norm_b, Zb);
  k_ssmk  <<<dim3(4, Hq), 256, 0, stream>>>(log_dt, A_re, A_im, C_re, C_im, Kbuf);
  k_conv  <<<dim3(2, Hq), 256, 0, stream>>>(Zb, Kbuf, Dp, Cb);
  k_fuse  <<<dim3(16, Bq), 512, 0, stream>>>(Cb, wb, out_b, wb + 65536, lin1_b,
                                             wb + 131072, lin2_b, Ax, out);
}